// Round 1
// baseline (907.107 us; speedup 1.0000x reference)
//
#include <hip/hip_runtime.h>
#include <hip/hip_bf16.h>

// Problem constants (B,T,D,H,KD) = (8,1024,512,8,64), SIGMA=1.
// d_out layout: out [8*1024*512] floats, then attn_weights [8*8*1024*1024] floats.
// Workspace layout (floats): qh, kh, vh, attn (4x 4194304) + q2, k2 (2x 65536) = 67.6 MB.

#define TSIZE 1024
#define DDIM  512
#define HKD   512

// ---------------------------------------------------------------------------
// Generic fp32 GEMM: C[M,N] = A[M,K] @ B[K,N].  Block tile 128x64, thread 8x4,
// BK=16, 256 threads.  All problem dims divide the tiles exactly.
// ---------------------------------------------------------------------------
__global__ __launch_bounds__(256) void gemm_f32(
    const float* __restrict__ A, const float* __restrict__ Bm, float* __restrict__ C,
    int K, int lda, int ldb, int ldc)
{
    __shared__ float As[16][128 + 4];  // [k][m], row=528B (16B aligned)
    __shared__ float Bs[16][64 + 4];   // [k][n], row=272B (16B aligned)
    const int tid  = threadIdx.x;
    const int row0 = blockIdx.y * 128;
    const int col0 = blockIdx.x * 64;

    const int a_k = tid & 15;   // 0..15
    const int a_r = tid >> 4;   // 0..15
    const int b_c = tid & 63;   // 0..63
    const int b_r = tid >> 6;   // 0..3

    const int trow = (tid >> 4) * 8;  // 0..120
    const int tcol = (tid & 15) * 4;  // 0..60

    float acc[8][4] = {};

    for (int k0 = 0; k0 < K; k0 += 16) {
#pragma unroll
        for (int r = 0; r < 8; ++r)
            As[a_k][a_r + r * 16] = A[(size_t)(row0 + a_r + r * 16) * lda + k0 + a_k];
#pragma unroll
        for (int r = 0; r < 4; ++r)
            Bs[b_r + r * 4][b_c] = Bm[(size_t)(k0 + b_r + r * 4) * ldb + col0 + b_c];
        __syncthreads();
#pragma unroll
        for (int kk = 0; kk < 16; ++kk) {
            float4 a0 = *(const float4*)&As[kk][trow];
            float4 a1 = *(const float4*)&As[kk][trow + 4];
            float4 b0 = *(const float4*)&Bs[kk][tcol];
            float a[8] = {a0.x, a0.y, a0.z, a0.w, a1.x, a1.y, a1.z, a1.w};
            float b[4] = {b0.x, b0.y, b0.z, b0.w};
#pragma unroll
            for (int i = 0; i < 8; ++i)
#pragma unroll
                for (int j = 0; j < 4; ++j)
                    acc[i][j] = fmaf(a[i], b[j], acc[i][j]);
        }
        __syncthreads();
    }
#pragma unroll
    for (int i = 0; i < 8; ++i) {
        float4 v = make_float4(acc[i][0], acc[i][1], acc[i][2], acc[i][3]);
        *(float4*)&C[(size_t)(row0 + trow + i) * ldc + col0 + tcol] = v;
    }
}

// ---------------------------------------------------------------------------
// Squared norms per (b,h,t): q2[(b*8+h)*1024+t] = sum_d qh[b,t,h,d]^2.
// One wave per row m=(b*1024+t); lane covers 8 consecutive d; shuffle-reduce
// within groups of 8 lanes (one head per group).
// ---------------------------------------------------------------------------
__global__ __launch_bounds__(256) void sqnorm_kernel(
    const float* __restrict__ qh, const float* __restrict__ kh,
    float* __restrict__ q2, float* __restrict__ k2)
{
    const int wave = threadIdx.x >> 6;
    const int lane = threadIdx.x & 63;
    const int m = blockIdx.x * 4 + wave;  // 0..8191
    const int b = m >> 10, t = m & 1023;

    const float* qp = qh + (size_t)m * HKD + lane * 8;
    const float* kp = kh + (size_t)m * HKD + lane * 8;
    float4 a0 = *(const float4*)qp, a1 = *(const float4*)(qp + 4);
    float4 c0 = *(const float4*)kp, c1 = *(const float4*)(kp + 4);
    float sq = a0.x*a0.x + a0.y*a0.y + a0.z*a0.z + a0.w*a0.w
             + a1.x*a1.x + a1.y*a1.y + a1.z*a1.z + a1.w*a1.w;
    float sk = c0.x*c0.x + c0.y*c0.y + c0.z*c0.z + c0.w*c0.w
             + c1.x*c1.x + c1.y*c1.y + c1.z*c1.z + c1.w*c1.w;
#pragma unroll
    for (int off = 1; off < 8; off <<= 1) {
        sq += __shfl_xor(sq, off);
        sk += __shfl_xor(sk, off);
    }
    if ((lane & 7) == 0) {
        int h = lane >> 3;
        q2[(size_t)(b * 8 + h) * TSIZE + t] = sq;
        k2[(size_t)(b * 8 + h) * TSIZE + t] = sk;
    }
}

// ---------------------------------------------------------------------------
// RBF scores: S[b,h,t,T] = exp(2*q.k - |q|^2 - |k|^2).  Per (b,h): GEMM-ish
// 64x64 output tile, K=64 fully resident in LDS (transposed: [d][row]).
// grid (16,16,64), 256 threads, 4x4 per thread.
// ---------------------------------------------------------------------------
__global__ __launch_bounds__(256) void rbf_kernel(
    const float* __restrict__ qh, const float* __restrict__ kh,
    const float* __restrict__ q2, const float* __restrict__ k2,
    float* __restrict__ S)
{
    __shared__ float Qs[64][64 + 4];  // [d][row]
    __shared__ float Ks[64][64 + 4];  // [d][col]
    const int tid = threadIdx.x;
    const int z = blockIdx.z;         // b*8+h
    const int b = z >> 3, h = z & 7;
    const int row0 = blockIdx.y * 64;
    const int col0 = blockIdx.x * 64;

    const float* Q  = qh + (size_t)b * TSIZE * HKD + h * 64;
    const float* Kp = kh + (size_t)b * TSIZE * HKD + h * 64;

    const int lr = tid >> 4;          // 0..15
    const int lc = (tid & 15) * 4;    // d: 0..60
#pragma unroll
    for (int r = 0; r < 4; ++r) {
        int row = lr + r * 16;
        float4 v = *(const float4*)&Q[(size_t)(row0 + row) * HKD + lc];
        Qs[lc + 0][row] = v.x; Qs[lc + 1][row] = v.y;
        Qs[lc + 2][row] = v.z; Qs[lc + 3][row] = v.w;
        float4 w = *(const float4*)&Kp[(size_t)(col0 + row) * HKD + lc];
        Ks[lc + 0][row] = w.x; Ks[lc + 1][row] = w.y;
        Ks[lc + 2][row] = w.z; Ks[lc + 3][row] = w.w;
    }
    __syncthreads();

    const int trow = (tid >> 4) * 4;
    const int tcol = (tid & 15) * 4;
    float acc[4][4] = {};
#pragma unroll 16
    for (int d = 0; d < 64; ++d) {
        float4 a4 = *(const float4*)&Qs[d][trow];
        float4 b4 = *(const float4*)&Ks[d][tcol];
        float a[4] = {a4.x, a4.y, a4.z, a4.w};
        float b[4] = {b4.x, b4.y, b4.z, b4.w};
#pragma unroll
        for (int i = 0; i < 4; ++i)
#pragma unroll
            for (int j = 0; j < 4; ++j)
                acc[i][j] = fmaf(a[i], b[j], acc[i][j]);
    }

    const float* q2p = q2 + (size_t)z * TSIZE;
    const float* k2p = k2 + (size_t)z * TSIZE;
    float qr[4], kc[4];
#pragma unroll
    for (int i = 0; i < 4; ++i) qr[i] = q2p[row0 + trow + i];
#pragma unroll
    for (int j = 0; j < 4; ++j) kc[j] = k2p[col0 + tcol + j];

    float* Sp = S + (size_t)z * TSIZE * TSIZE;
#pragma unroll
    for (int i = 0; i < 4; ++i) {
        float4 v;
        v.x = __expf(2.f * acc[i][0] - qr[i] - kc[0]);
        v.y = __expf(2.f * acc[i][1] - qr[i] - kc[1]);
        v.z = __expf(2.f * acc[i][2] - qr[i] - kc[2]);
        v.w = __expf(2.f * acc[i][3] - qr[i] - kc[3]);
        *(float4*)&Sp[(size_t)(row0 + trow + i) * TSIZE + col0 + tcol] = v;
    }
}

// ---------------------------------------------------------------------------
// attn[b,t,h,:] = sum_T S[b,h,t,T] * vh[b,T,h,:].  Per z=(b*8+h): GEMM
// [1024x1024]@[1024x64].  grid (1,8,64); same tiling as gemm_f32.
// ---------------------------------------------------------------------------
__global__ __launch_bounds__(256) void attnv_kernel(
    const float* __restrict__ S, const float* __restrict__ vh, float* __restrict__ attn)
{
    __shared__ float As[16][128 + 4];
    __shared__ float Bs[16][64 + 4];
    const int tid = threadIdx.x;
    const int z = blockIdx.z;
    const int b = z >> 3, h = z & 7;
    const float* A  = S    + (size_t)z * TSIZE * TSIZE;          // lda = 1024
    const float* Bm = vh   + (size_t)b * TSIZE * HKD + h * 64;   // ldb = 512
    float*       C  = attn + (size_t)b * TSIZE * HKD + h * 64;   // ldc = 512
    const int row0 = blockIdx.y * 128;

    const int a_k = tid & 15;
    const int a_r = tid >> 4;
    const int b_c = tid & 63;
    const int b_r = tid >> 6;
    const int trow = (tid >> 4) * 8;
    const int tcol = (tid & 15) * 4;

    float acc[8][4] = {};
    for (int k0 = 0; k0 < TSIZE; k0 += 16) {
#pragma unroll
        for (int r = 0; r < 8; ++r)
            As[a_k][a_r + r * 16] = A[(size_t)(row0 + a_r + r * 16) * TSIZE + k0 + a_k];
#pragma unroll
        for (int r = 0; r < 4; ++r)
            Bs[b_r + r * 4][b_c] = Bm[(size_t)(k0 + b_r + r * 4) * HKD + b_c];
        __syncthreads();
#pragma unroll
        for (int kk = 0; kk < 16; ++kk) {
            float4 a0 = *(const float4*)&As[kk][trow];
            float4 a1 = *(const float4*)&As[kk][trow + 4];
            float4 b0 = *(const float4*)&Bs[kk][tcol];
            float a[8] = {a0.x, a0.y, a0.z, a0.w, a1.x, a1.y, a1.z, a1.w};
            float bb[4] = {b0.x, b0.y, b0.z, b0.w};
#pragma unroll
            for (int i = 0; i < 8; ++i)
#pragma unroll
                for (int j = 0; j < 4; ++j)
                    acc[i][j] = fmaf(a[i], bb[j], acc[i][j]);
        }
        __syncthreads();
    }
#pragma unroll
    for (int i = 0; i < 8; ++i) {
        float4 v = make_float4(acc[i][0], acc[i][1], acc[i][2], acc[i][3]);
        *(float4*)&C[(size_t)(row0 + trow + i) * HKD + tcol] = v;
    }
}

extern "C" void kernel_launch(void* const* d_in, const int* in_sizes, int n_in,
                              void* d_out, int out_size, void* d_ws, size_t ws_size,
                              hipStream_t stream)
{
    const float* query = (const float*)d_in[0];
    const float* key   = (const float*)d_in[1];
    const float* value = (const float*)d_in[2];
    const float* Wq    = (const float*)d_in[3];
    const float* Wk    = (const float*)d_in[4];
    const float* Wv    = (const float*)d_in[5];
    const float* Wo    = (const float*)d_in[6];

    float* out  = (float*)d_out;                       // [8,1024,512]
    float* Sout = out + (size_t)8 * 1024 * 512;        // [8,8,1024,1024]

    float* ws   = (float*)d_ws;
    float* qh   = ws;                                  // [8192,512]
    float* kh   = qh + (size_t)8192 * 512;
    float* vh   = kh + (size_t)8192 * 512;
    float* attn = vh + (size_t)8192 * 512;
    float* q2   = attn + (size_t)8192 * 512;           // [64,1024]
    float* k2   = q2 + (size_t)64 * 1024;

    // Projections: [8192,512] @ [512,512]
    gemm_f32<<<dim3(8, 64), 256, 0, stream>>>(query, Wq, qh, 512, 512, 512, 512);
    gemm_f32<<<dim3(8, 64), 256, 0, stream>>>(key,   Wk, kh, 512, 512, 512, 512);
    gemm_f32<<<dim3(8, 64), 256, 0, stream>>>(value, Wv, vh, 512, 512, 512, 512);

    // Row squared norms per head.
    sqnorm_kernel<<<2048, 256, 0, stream>>>(qh, kh, q2, k2);

    // RBF scores -> second output region.
    rbf_kernel<<<dim3(16, 16, 64), 256, 0, stream>>>(qh, kh, q2, k2, Sout);

    // attn = S @ V per (b,h).
    attnv_kernel<<<dim3(1, 8, 64), 256, 0, stream>>>(Sout, vh, attn);

    // out = attn @ Wo.
    gemm_f32<<<dim3(8, 64), 256, 0, stream>>>(attn, Wo, out, 512, 512, 512, 512);
}

// Round 2
// 717.390 us; speedup vs baseline: 1.2645x; 1.2645x over previous
//
#include <hip/hip_runtime.h>

// (B,T,D,H,KD)=(8,1024,512,8,64), SIGMA=1.
// d_out: out [8*1024*512] f32, then attn_weights [64][1024][1024] f32.
// Strategy: split-bf16 (hi+lo) MFMA for the q/k path (precision-critical:
// S=exp(-l2) needs dl2<~0.02), plain bf16 MFMA for v/S/attn/Wo path.

typedef float  floatx4 __attribute__((ext_vector_type(4)));
typedef short  short8  __attribute__((ext_vector_type(8)));
typedef unsigned short ushort_t;

#define MFMA16(a, b, c) __builtin_amdgcn_mfma_f32_16x16x32_bf16((a), (b), (c), 0, 0, 0)

__device__ inline ushort_t f2b(float f) {  // f32 -> bf16 bits, RNE
    unsigned u = __builtin_bit_cast(unsigned, f);
    unsigned r = u + 0x7fffu + ((u >> 16) & 1u);
    return (ushort_t)(r >> 16);
}
__device__ inline float b2f(ushort_t s) {  // bf16 bits -> f32 (exact)
    return __builtin_bit_cast(float, (unsigned)s << 16);
}

// ---------------------------------------------------------------------------
// Weight transpose + split: WT[n][k] = W[k][n]; hi=bf16(w), lo=bf16(w-hi).
// blockIdx.y selects matrix: 0=Wq(split) 1=Wk(split) 2=Wv 3=Wo.
// ---------------------------------------------------------------------------
__global__ __launch_bounds__(256) void wt_cvt(
    const float* __restrict__ Wq, const float* __restrict__ Wk,
    const float* __restrict__ Wv, const float* __restrict__ Wo,
    ushort_t* __restrict__ qTh, ushort_t* __restrict__ qTl,
    ushort_t* __restrict__ kTh, ushort_t* __restrict__ kTl,
    ushort_t* __restrict__ vT,  ushort_t* __restrict__ oT)
{
    const int idx = blockIdx.x * 256 + threadIdx.x;  // n*512+k
    const int n = idx >> 9, k = idx & 511;
    const float* W; ushort_t* H; ushort_t* L; bool wl;
    switch (blockIdx.y) {
        case 0:  W = Wq; H = qTh; L = qTl; wl = true;  break;
        case 1:  W = Wk; H = kTh; L = kTl; wl = true;  break;
        case 2:  W = Wv; H = vT;  L = vT;  wl = false; break;
        default: W = Wo; H = oT;  L = oT;  wl = false; break;
    }
    float f = W[(size_t)k * 512 + n];
    ushort_t h = f2b(f);
    H[idx] = h;
    if (wl) L[idx] = f2b(f - b2f(h));
}

// ---------------------------------------------------------------------------
// MFMA GEMM, K=512 fixed, tile 64x64 per block (4 waves, wave = 16 rows).
// AT=float: A fp32, converted to hi/lo bf16 in-register (NPASS=3 uses lo).
// AT=ushort_t: A already bf16.
// OUTMODE 0: f32 row-major.  1: bf16 hi+lo pair.  2: vhT[z][d][T] bf16.
// ---------------------------------------------------------------------------
template <typename AT, int NPASS, int OUTMODE>
__global__ __launch_bounds__(256) void mfma_gemm512(
    const AT* __restrict__ A, const ushort_t* __restrict__ BTh,
    const ushort_t* __restrict__ BTl, float* __restrict__ outF,
    ushort_t* __restrict__ outH, ushort_t* __restrict__ outL)
{
    const int tid = threadIdx.x;
    const int w = tid >> 6, lane = tid & 63;
    const int l15 = lane & 15, quad = lane >> 4;
    const int m0 = blockIdx.y * 64, n0 = blockIdx.x * 64;
    const int mrow = m0 + 16 * w + l15;

    floatx4 acc[4];
#pragma unroll
    for (int i = 0; i < 4; ++i) acc[i] = (floatx4){0.f, 0.f, 0.f, 0.f};

    for (int k0 = 0; k0 < 512; k0 += 32) {
        const int kk = k0 + quad * 8;
        short8 ah, al;
        if constexpr (sizeof(AT) == 4) {  // fp32 A: split in-register
            const float* ap = (const float*)A + (size_t)mrow * 512 + kk;
            float4 f0 = *(const float4*)ap;
            float4 f1 = *(const float4*)(ap + 4);
            float fv[8] = {f0.x, f0.y, f0.z, f0.w, f1.x, f1.y, f1.z, f1.w};
#pragma unroll
            for (int j = 0; j < 8; ++j) {
                ushort_t h = f2b(fv[j]);
                ah[j] = (short)h;
                if (NPASS == 3) al[j] = (short)f2b(fv[j] - b2f(h));
            }
        } else {
            ah = *(const short8*)((const ushort_t*)A + (size_t)mrow * 512 + kk);
        }
#pragma unroll
        for (int ct = 0; ct < 4; ++ct) {
            const int n = n0 + ct * 16 + l15;
            short8 bh = *(const short8*)(BTh + (size_t)n * 512 + kk);
            acc[ct] = MFMA16(ah, bh, acc[ct]);
            if (NPASS == 3) {
                short8 bl = *(const short8*)(BTl + (size_t)n * 512 + kk);
                acc[ct] = MFMA16(al, bh, acc[ct]);
                acc[ct] = MFMA16(ah, bl, acc[ct]);
            }
        }
    }

#pragma unroll
    for (int ct = 0; ct < 4; ++ct) {
        const int n = n0 + ct * 16 + l15;
#pragma unroll
        for (int r = 0; r < 4; ++r) {
            const int m = m0 + 16 * w + quad * 4 + r;
            const float v = acc[ct][r];
            if (OUTMODE == 0) {
                outF[(size_t)m * 512 + n] = v;
            } else if (OUTMODE == 1) {
                ushort_t h = f2b(v);
                outH[(size_t)m * 512 + n] = h;
                outL[(size_t)m * 512 + n] = f2b(v - b2f(h));
            } else {  // vhT[z=b*8+h][d][t]
                const int b = m >> 10, t = m & 1023, hh = n >> 6, d = n & 63;
                outH[((size_t)(b * 8 + hh) * 64 + d) * 1024 + t] = f2b(v);
            }
        }
    }
}

// ---------------------------------------------------------------------------
// Per-head squared norms from hi+lo bf16: q2[z][t] = sum_d (hi+lo)^2.
// ---------------------------------------------------------------------------
__global__ __launch_bounds__(256) void q2k2_kernel(
    const ushort_t* __restrict__ qh_hi, const ushort_t* __restrict__ qh_lo,
    const ushort_t* __restrict__ kh_hi, const ushort_t* __restrict__ kh_lo,
    float* __restrict__ q2, float* __restrict__ k2)
{
    const int wave = threadIdx.x >> 6, lane = threadIdx.x & 63;
    const int m = blockIdx.x * 4 + wave;  // 0..8191
    const int b = m >> 10, t = m & 1023;
    const size_t base = (size_t)m * 512 + lane * 8;

    float sq = 0.f, sk = 0.f;
    short8 qh = *(const short8*)(qh_hi + base);
    short8 ql = *(const short8*)(qh_lo + base);
    short8 kh = *(const short8*)(kh_hi + base);
    short8 kl = *(const short8*)(kh_lo + base);
#pragma unroll
    for (int j = 0; j < 8; ++j) {
        float qv = b2f((ushort_t)qh[j]) + b2f((ushort_t)ql[j]);
        float kv = b2f((ushort_t)kh[j]) + b2f((ushort_t)kl[j]);
        sq = fmaf(qv, qv, sq);
        sk = fmaf(kv, kv, sk);
    }
#pragma unroll
    for (int off = 1; off < 8; off <<= 1) {
        sq += __shfl_xor(sq, off);
        sk += __shfl_xor(sk, off);
    }
    if ((lane & 7) == 0) {
        const int h = lane >> 3;
        q2[(size_t)(b * 8 + h) * 1024 + t] = sq;
        k2[(size_t)(b * 8 + h) * 1024 + t] = sk;
    }
}

// ---------------------------------------------------------------------------
// Fused flash: per block (z, 64 q-rows).  For each 64-col tile: QK^T via
// 3-pass split MFMA -> exp -> store S fp32 + stash bf16 P in per-wave LDS
// strip (C-layout -> A-layout round-trip) -> S@V MFMA into O regs.
// No __syncthreads: each wave reads only the LDS strip it wrote.
// ---------------------------------------------------------------------------
__global__ __launch_bounds__(256) void flash_rbf(
    const ushort_t* __restrict__ qh_hi, const ushort_t* __restrict__ qh_lo,
    const ushort_t* __restrict__ kh_hi, const ushort_t* __restrict__ kh_lo,
    const ushort_t* __restrict__ vhT, const float* __restrict__ q2,
    const float* __restrict__ k2, float* __restrict__ S,
    ushort_t* __restrict__ attn)
{
    __shared__ ushort_t P[64 * 72];  // row stride 72 shorts = 144 B (16B-mult)

    const int tid = threadIdx.x;
    const int w = tid >> 6, lane = tid & 63;
    const int l15 = lane & 15, quad = lane >> 4;
    const int z = blockIdx.y, b = z >> 3, h = z & 7;
    const int q0 = blockIdx.x * 64;

    // Q fragments (fixed for the whole block).
    const size_t qrow = (size_t)(b * 1024 + q0 + 16 * w + l15) * 512 + h * 64 + quad * 8;
    short8 aqh[2], aql[2];
    aqh[0] = *(const short8*)(qh_hi + qrow);
    aqh[1] = *(const short8*)(qh_hi + qrow + 32);
    aql[0] = *(const short8*)(qh_lo + qrow);
    aql[1] = *(const short8*)(qh_lo + qrow + 32);

    float q2v[4];
#pragma unroll
    for (int r = 0; r < 4; ++r)
        q2v[r] = q2[(size_t)z * 1024 + q0 + 16 * w + quad * 4 + r];

    floatx4 oacc[4];
#pragma unroll
    for (int i = 0; i < 4; ++i) oacc[i] = (floatx4){0.f, 0.f, 0.f, 0.f};

    const size_t Sz = (size_t)z << 20;  // z*1024*1024

    for (int ct = 0; ct < 16; ++ct) {
        const int col0 = ct * 64;
#pragma unroll
        for (int j = 0; j < 4; ++j) {
            const int n = col0 + j * 16 + l15;
            const size_t krow = (size_t)(b * 1024 + n) * 512 + h * 64 + quad * 8;
            short8 kb0 = *(const short8*)(kh_hi + krow);
            short8 kb1 = *(const short8*)(kh_hi + krow + 32);
            short8 kl0 = *(const short8*)(kh_lo + krow);
            short8 kl1 = *(const short8*)(kh_lo + krow + 32);
            floatx4 s = (floatx4){0.f, 0.f, 0.f, 0.f};
            s = MFMA16(aqh[0], kb0, s);
            s = MFMA16(aqh[1], kb1, s);
            s = MFMA16(aql[0], kb0, s);
            s = MFMA16(aql[1], kb1, s);
            s = MFMA16(aqh[0], kl0, s);
            s = MFMA16(aqh[1], kl1, s);
            const float k2v = k2[(size_t)z * 1024 + n];
#pragma unroll
            for (int r = 0; r < 4; ++r) {
                const float val = __expf(2.f * s[r] - q2v[r] - k2v);
                const int row = q0 + 16 * w + quad * 4 + r;
                S[Sz + (size_t)row * 1024 + n] = val;
                P[(16 * w + quad * 4 + r) * 72 + j * 16 + l15] = f2b(val);
            }
        }
        // Same-wave LDS RAW: compiler inserts lgkmcnt waits; no barrier needed.
        short8 pf0 = *(const short8*)&P[(16 * w + l15) * 72 + quad * 8];
        short8 pf1 = *(const short8*)&P[(16 * w + l15) * 72 + 32 + quad * 8];
#pragma unroll
        for (int j2 = 0; j2 < 4; ++j2) {
            const int d = j2 * 16 + l15;
            const size_t vrow = ((size_t)z * 64 + d) * 1024 + col0 + quad * 8;
            short8 gv0 = *(const short8*)(vhT + vrow);
            short8 gv1 = *(const short8*)(vhT + vrow + 32);
            oacc[j2] = MFMA16(pf0, gv0, oacc[j2]);
            oacc[j2] = MFMA16(pf1, gv1, oacc[j2]);
        }
    }

#pragma unroll
    for (int j2 = 0; j2 < 4; ++j2)
#pragma unroll
        for (int r = 0; r < 4; ++r) {
            const int row = q0 + 16 * w + quad * 4 + r;
            attn[(size_t)(b * 1024 + row) * 512 + h * 64 + j2 * 16 + l15] =
                f2b(oacc[j2][r]);
        }
}

extern "C" void kernel_launch(void* const* d_in, const int* in_sizes, int n_in,
                              void* d_out, int out_size, void* d_ws, size_t ws_size,
                              hipStream_t stream)
{
    const float* query = (const float*)d_in[0];
    const float* key   = (const float*)d_in[1];
    const float* value = (const float*)d_in[2];
    const float* Wq    = (const float*)d_in[3];
    const float* Wk    = (const float*)d_in[4];
    const float* Wv    = (const float*)d_in[5];
    const float* Wo    = (const float*)d_in[6];

    float* out  = (float*)d_out;                 // [8192,512]
    float* Sout = out + (size_t)8192 * 512;      // [64,1024,1024]

    // Workspace: 6x 4M-ushort + 6x 256K-ushort + 2x 64K-float = ~51.5 MB.
    const size_t NE = (size_t)8192 * 512;        // 4194304
    ushort_t* qh_hi   = (ushort_t*)d_ws;
    ushort_t* qh_lo   = qh_hi + NE;
    ushort_t* kh_hi   = qh_lo + NE;
    ushort_t* kh_lo   = kh_hi + NE;
    ushort_t* vhT     = kh_lo + NE;              // [64][64][1024]
    ushort_t* attn_bf = vhT + NE;                // [8192][512]
    ushort_t* WqT_hi  = attn_bf + NE;            // each [512][512]
    ushort_t* WqT_lo  = WqT_hi + 262144;
    ushort_t* WkT_hi  = WqT_lo + 262144;
    ushort_t* WkT_lo  = WkT_hi + 262144;
    ushort_t* WvT     = WkT_lo + 262144;
    ushort_t* WoT     = WvT + 262144;
    float*    q2      = (float*)(WoT + 262144);  // [64][1024]
    float*    k2      = q2 + 65536;

    // 1. Weight transpose + split.
    wt_cvt<<<dim3(1024, 4), 256, 0, stream>>>(Wq, Wk, Wv, Wo, WqT_hi, WqT_lo,
                                              WkT_hi, WkT_lo, WvT, WoT);

    // 2. Projections.  q,k: 3-pass split.  v: 1-pass, transposed bf16 out.
    mfma_gemm512<float, 3, 1><<<dim3(8, 128), 256, 0, stream>>>(
        query, WqT_hi, WqT_lo, nullptr, qh_hi, qh_lo);
    mfma_gemm512<float, 3, 1><<<dim3(8, 128), 256, 0, stream>>>(
        key, WkT_hi, WkT_lo, nullptr, kh_hi, kh_lo);
    mfma_gemm512<float, 1, 2><<<dim3(8, 128), 256, 0, stream>>>(
        value, WvT, nullptr, nullptr, vhT, nullptr);

    // 3. Squared norms.
    q2k2_kernel<<<2048, 256, 0, stream>>>(qh_hi, qh_lo, kh_hi, kh_lo, q2, k2);

    // 4. Fused RBF-score + S@V.
    flash_rbf<<<dim3(16, 64), 256, 0, stream>>>(qh_hi, qh_lo, kh_hi, kh_lo,
                                                vhT, q2, k2, Sout, attn_bf);

    // 5. Output projection: out = attn @ Wo (1-pass bf16, f32 out).
    mfma_gemm512<ushort_t, 1, 0><<<dim3(8, 128), 256, 0, stream>>>(
        attn_bf, WoT, nullptr, out, nullptr, nullptr);
}

// Round 3
// 702.977 us; speedup vs baseline: 1.2904x; 1.0205x over previous
//
#include <hip/hip_runtime.h>

// (B,T,D,H,KD)=(8,1024,512,8,64), SIGMA=1.
// d_out: out [8*1024*512] f32, then attn_weights [64][1024][1024] f32.
// Split-bf16 (hi+lo, 3-pass MFMA) for the precision-critical q/k path,
// plain bf16 MFMA for v/S/attn/Wo.  R3: XCD-aware swizzles + load hoisting.

typedef float  floatx4 __attribute__((ext_vector_type(4)));
typedef short  short8  __attribute__((ext_vector_type(8)));
typedef unsigned short ushort_t;

#define MFMA16(a, b, c) __builtin_amdgcn_mfma_f32_16x16x32_bf16((a), (b), (c), 0, 0, 0)

__device__ inline ushort_t f2b(float f) {  // f32 -> bf16 bits, RNE
    unsigned u = __builtin_bit_cast(unsigned, f);
    unsigned r = u + 0x7fffu + ((u >> 16) & 1u);
    return (ushort_t)(r >> 16);
}
__device__ inline ushort_t f2b_trunc(float f) {  // truncate (P only)
    return (ushort_t)(__builtin_bit_cast(unsigned, f) >> 16);
}
__device__ inline float b2f(ushort_t s) {
    return __builtin_bit_cast(float, (unsigned)s << 16);
}

// ---------------------------------------------------------------------------
// Weight transpose + split: WT[n][k] = W[k][n]; hi=bf16(w), lo=bf16(w-hi).
// blockIdx.y: 0=Wq(split) 1=Wk(split) 2=Wv 3=Wo.
// ---------------------------------------------------------------------------
__global__ __launch_bounds__(256) void wt_cvt(
    const float* __restrict__ Wq, const float* __restrict__ Wk,
    const float* __restrict__ Wv, const float* __restrict__ Wo,
    ushort_t* __restrict__ qTh, ushort_t* __restrict__ qTl,
    ushort_t* __restrict__ kTh, ushort_t* __restrict__ kTl,
    ushort_t* __restrict__ vT,  ushort_t* __restrict__ oT)
{
    const int idx = blockIdx.x * 256 + threadIdx.x;  // n*512+k
    const int n = idx >> 9, k = idx & 511;
    const float* W; ushort_t* H; ushort_t* L; bool wl;
    switch (blockIdx.y) {
        case 0:  W = Wq; H = qTh; L = qTl; wl = true;  break;
        case 1:  W = Wk; H = kTh; L = kTl; wl = true;  break;
        case 2:  W = Wv; H = vT;  L = vT;  wl = false; break;
        default: W = Wo; H = oT;  L = oT;  wl = false; break;
    }
    float f = W[(size_t)k * 512 + n];
    ushort_t h = f2b(f);
    H[idx] = h;
    if (wl) L[idx] = f2b(f - b2f(h));
}

// ---------------------------------------------------------------------------
// MFMA GEMM, K=512, 64x64 tile/block (4 waves).  fp32 A split in-register.
// 1-D grid, swizzled so blocks sharing an A-slice share an XCD:
// gid = n0*128 + m_tile  ->  gid%8 == m_tile%8.
// All frag loads hoisted ahead of the MFMA block.
// OUTMODE 0: f32.  1: bf16 hi+lo.  2: vhT[z][d][T] bf16.
// ---------------------------------------------------------------------------
template <typename AT, int NPASS, int OUTMODE>
__global__ __launch_bounds__(256) void mfma_gemm512(
    const AT* __restrict__ A, const ushort_t* __restrict__ BTh,
    const ushort_t* __restrict__ BTl, float* __restrict__ outF,
    ushort_t* __restrict__ outH, ushort_t* __restrict__ outL)
{
    const int tid = threadIdx.x;
    const int w = tid >> 6, lane = tid & 63;
    const int l15 = lane & 15, quad = lane >> 4;
    const int gid = blockIdx.x;
    const int n0 = (gid >> 7) * 64;
    const int m0 = (gid & 127) * 64;
    const int mrow = m0 + 16 * w + l15;

    floatx4 acc[4];
#pragma unroll
    for (int i = 0; i < 4; ++i) acc[i] = (floatx4){0.f, 0.f, 0.f, 0.f};

    for (int k0 = 0; k0 < 512; k0 += 32) {
        const int kk = k0 + quad * 8;
        // --- all loads first ---
        short8 ah, al;
        if constexpr (sizeof(AT) == 4) {
            const float* ap = (const float*)A + (size_t)mrow * 512 + kk;
            float4 f0 = *(const float4*)ap;
            float4 f1 = *(const float4*)(ap + 4);
            float fv[8] = {f0.x, f0.y, f0.z, f0.w, f1.x, f1.y, f1.z, f1.w};
#pragma unroll
            for (int j = 0; j < 8; ++j) {
                ushort_t h = f2b(fv[j]);
                ah[j] = (short)h;
                if (NPASS == 3) al[j] = (short)f2b(fv[j] - b2f(h));
            }
        } else {
            ah = *(const short8*)((const ushort_t*)A + (size_t)mrow * 512 + kk);
        }
        short8 bh[4], bl[4];
#pragma unroll
        for (int ct = 0; ct < 4; ++ct) {
            const int n = n0 + ct * 16 + l15;
            bh[ct] = *(const short8*)(BTh + (size_t)n * 512 + kk);
            if (NPASS == 3) bl[ct] = *(const short8*)(BTl + (size_t)n * 512 + kk);
        }
        // --- MFMA block ---
#pragma unroll
        for (int ct = 0; ct < 4; ++ct) {
            acc[ct] = MFMA16(ah, bh[ct], acc[ct]);
            if (NPASS == 3) {
                acc[ct] = MFMA16(al, bh[ct], acc[ct]);
                acc[ct] = MFMA16(ah, bl[ct], acc[ct]);
            }
        }
    }

#pragma unroll
    for (int ct = 0; ct < 4; ++ct) {
        const int n = n0 + ct * 16 + l15;
#pragma unroll
        for (int r = 0; r < 4; ++r) {
            const int m = m0 + 16 * w + quad * 4 + r;
            const float v = acc[ct][r];
            if (OUTMODE == 0) {
                outF[(size_t)m * 512 + n] = v;
            } else if (OUTMODE == 1) {
                ushort_t h = f2b(v);
                outH[(size_t)m * 512 + n] = h;
                outL[(size_t)m * 512 + n] = f2b(v - b2f(h));
            } else {
                const int b = m >> 10, t = m & 1023, hh = n >> 6, d = n & 63;
                outH[((size_t)(b * 8 + hh) * 64 + d) * 1024 + t] = f2b(v);
            }
        }
    }
}

// ---------------------------------------------------------------------------
// Per-head squared norms: q2[z][t] = sum_d (hi+lo)^2.
// ---------------------------------------------------------------------------
__global__ __launch_bounds__(256) void q2k2_kernel(
    const ushort_t* __restrict__ qh_hi, const ushort_t* __restrict__ qh_lo,
    const ushort_t* __restrict__ kh_hi, const ushort_t* __restrict__ kh_lo,
    float* __restrict__ q2, float* __restrict__ k2)
{
    const int wave = threadIdx.x >> 6, lane = threadIdx.x & 63;
    const int m = blockIdx.x * 4 + wave;
    const int b = m >> 10, t = m & 1023;
    const size_t base = (size_t)m * 512 + lane * 8;

    float sq = 0.f, sk = 0.f;
    short8 qh = *(const short8*)(qh_hi + base);
    short8 ql = *(const short8*)(qh_lo + base);
    short8 kh = *(const short8*)(kh_hi + base);
    short8 kl = *(const short8*)(kh_lo + base);
#pragma unroll
    for (int j = 0; j < 8; ++j) {
        float qv = b2f((ushort_t)qh[j]) + b2f((ushort_t)ql[j]);
        float kv = b2f((ushort_t)kh[j]) + b2f((ushort_t)kl[j]);
        sq = fmaf(qv, qv, sq);
        sk = fmaf(kv, kv, sk);
    }
#pragma unroll
    for (int off = 1; off < 8; off <<= 1) {
        sq += __shfl_xor(sq, off);
        sk += __shfl_xor(sk, off);
    }
    if ((lane & 7) == 0) {
        const int h = lane >> 3;
        q2[(size_t)(b * 8 + h) * 1024 + t] = sq;
        k2[(size_t)(b * 8 + h) * 1024 + t] = sk;
    }
}

// ---------------------------------------------------------------------------
// Fused flash: per block (z, 64 q-rows).  1-D grid, gid = qtile*64 + z so
// gid%8 == z%8: all 16 q-tiles of a z share one XCD's L2 (K/V stay hot).
// Per 64-col tile: hoisted K hi+lo frag loads -> 24 QK MFMAs -> V loads ->
// exp + S store + bf16 P to per-wave LDS strip -> P reads -> 8 SV MFMAs.
// ---------------------------------------------------------------------------
__global__ __launch_bounds__(256) void flash_rbf(
    const ushort_t* __restrict__ qh_hi, const ushort_t* __restrict__ qh_lo,
    const ushort_t* __restrict__ kh_hi, const ushort_t* __restrict__ kh_lo,
    const ushort_t* __restrict__ vhT, const float* __restrict__ q2,
    const float* __restrict__ k2, float* __restrict__ S,
    ushort_t* __restrict__ attn)
{
    __shared__ ushort_t P[64 * 72];

    const int tid = threadIdx.x;
    const int w = tid >> 6, lane = tid & 63;
    const int l15 = lane & 15, quad = lane >> 4;
    const int gid = blockIdx.x;
    const int z = gid & 63, qt = gid >> 6;
    const int b = z >> 3, h = z & 7;
    const int q0 = qt * 64;

    const size_t qrow = (size_t)(b * 1024 + q0 + 16 * w + l15) * 512 + h * 64 + quad * 8;
    short8 aqh[2], aql[2];
    aqh[0] = *(const short8*)(qh_hi + qrow);
    aqh[1] = *(const short8*)(qh_hi + qrow + 32);
    aql[0] = *(const short8*)(qh_lo + qrow);
    aql[1] = *(const short8*)(qh_lo + qrow + 32);

    float q2v[4];
#pragma unroll
    for (int r = 0; r < 4; ++r)
        q2v[r] = q2[(size_t)z * 1024 + q0 + 16 * w + quad * 4 + r];

    floatx4 oacc[4];
#pragma unroll
    for (int i = 0; i < 4; ++i) oacc[i] = (floatx4){0.f, 0.f, 0.f, 0.f};

    const size_t Sz = (size_t)z << 20;

    for (int ct = 0; ct < 16; ++ct) {
        const int col0 = ct * 64;

        // --- K fragment loads, all hoisted ---
        short8 kbh0[4], kbh1[4], kbl0[4], kbl1[4];
        size_t krowb[4];
#pragma unroll
        for (int j = 0; j < 4; ++j) {
            krowb[j] = (size_t)(b * 1024 + col0 + j * 16 + l15) * 512 + h * 64 + quad * 8;
            kbh0[j] = *(const short8*)(kh_hi + krowb[j]);
            kbh1[j] = *(const short8*)(kh_hi + krowb[j] + 32);
        }
#pragma unroll
        for (int j = 0; j < 4; ++j) {
            kbl0[j] = *(const short8*)(kh_lo + krowb[j]);
            kbl1[j] = *(const short8*)(kh_lo + krowb[j] + 32);
        }
        float k2v[4];
#pragma unroll
        for (int j = 0; j < 4; ++j)
            k2v[j] = k2[(size_t)z * 1024 + col0 + j * 16 + l15];

        // --- QK^T, 3-pass split, 4 independent chains ---
        floatx4 s[4];
#pragma unroll
        for (int j = 0; j < 4; ++j) {
            s[j] = (floatx4){0.f, 0.f, 0.f, 0.f};
            s[j] = MFMA16(aqh[0], kbh0[j], s[j]);
            s[j] = MFMA16(aqh[1], kbh1[j], s[j]);
            s[j] = MFMA16(aql[0], kbh0[j], s[j]);
            s[j] = MFMA16(aql[1], kbh1[j], s[j]);
            s[j] = MFMA16(aqh[0], kbl0[j], s[j]);
            s[j] = MFMA16(aqh[1], kbl1[j], s[j]);
        }

        // --- V loads (used after exp; latency hidden by VALU below) ---
        short8 gv0[4], gv1[4];
#pragma unroll
        for (int j2 = 0; j2 < 4; ++j2) {
            const size_t vrow = ((size_t)z * 64 + j2 * 16 + l15) * 1024 + col0 + quad * 8;
            gv0[j2] = *(const short8*)(vhT + vrow);
            gv1[j2] = *(const short8*)(vhT + vrow + 32);
        }

        // --- exp, S store, P pack ---
#pragma unroll
        for (int j = 0; j < 4; ++j) {
#pragma unroll
            for (int r = 0; r < 4; ++r) {
                const float val = __expf(2.f * s[j][r] - q2v[r] - k2v[j]);
                const int row = q0 + 16 * w + quad * 4 + r;
                S[Sz + (size_t)row * 1024 + col0 + j * 16 + l15] = val;
                P[(16 * w + quad * 4 + r) * 72 + j * 16 + l15] = f2b_trunc(val);
            }
        }

        // --- same-wave LDS readback (A-layout) + S@V ---
        short8 pf0 = *(const short8*)&P[(16 * w + l15) * 72 + quad * 8];
        short8 pf1 = *(const short8*)&P[(16 * w + l15) * 72 + 32 + quad * 8];
#pragma unroll
        for (int j2 = 0; j2 < 4; ++j2) {
            oacc[j2] = MFMA16(pf0, gv0[j2], oacc[j2]);
            oacc[j2] = MFMA16(pf1, gv1[j2], oacc[j2]);
        }
    }

#pragma unroll
    for (int j2 = 0; j2 < 4; ++j2)
#pragma unroll
        for (int r = 0; r < 4; ++r) {
            const int row = q0 + 16 * w + quad * 4 + r;
            attn[(size_t)(b * 1024 + row) * 512 + h * 64 + j2 * 16 + l15] =
                f2b(oacc[j2][r]);
        }
}

extern "C" void kernel_launch(void* const* d_in, const int* in_sizes, int n_in,
                              void* d_out, int out_size, void* d_ws, size_t ws_size,
                              hipStream_t stream)
{
    const float* query = (const float*)d_in[0];
    const float* key   = (const float*)d_in[1];
    const float* value = (const float*)d_in[2];
    const float* Wq    = (const float*)d_in[3];
    const float* Wk    = (const float*)d_in[4];
    const float* Wv    = (const float*)d_in[5];
    const float* Wo    = (const float*)d_in[6];

    float* out  = (float*)d_out;
    float* Sout = out + (size_t)8192 * 512;

    const size_t NE = (size_t)8192 * 512;
    ushort_t* qh_hi   = (ushort_t*)d_ws;
    ushort_t* qh_lo   = qh_hi + NE;
    ushort_t* kh_hi   = qh_lo + NE;
    ushort_t* kh_lo   = kh_hi + NE;
    ushort_t* vhT     = kh_lo + NE;
    ushort_t* attn_bf = vhT + NE;
    ushort_t* WqT_hi  = attn_bf + NE;
    ushort_t* WqT_lo  = WqT_hi + 262144;
    ushort_t* WkT_hi  = WqT_lo + 262144;
    ushort_t* WkT_lo  = WkT_hi + 262144;
    ushort_t* WvT     = WkT_lo + 262144;
    ushort_t* WoT     = WvT + 262144;
    float*    q2      = (float*)(WoT + 262144);
    float*    k2      = q2 + 65536;

    wt_cvt<<<dim3(1024, 4), 256, 0, stream>>>(Wq, Wk, Wv, Wo, WqT_hi, WqT_lo,
                                              WkT_hi, WkT_lo, WvT, WoT);

    mfma_gemm512<float, 3, 1><<<1024, 256, 0, stream>>>(
        query, WqT_hi, WqT_lo, nullptr, qh_hi, qh_lo);
    mfma_gemm512<float, 3, 1><<<1024, 256, 0, stream>>>(
        key, WkT_hi, WkT_lo, nullptr, kh_hi, kh_lo);
    mfma_gemm512<float, 1, 2><<<1024, 256, 0, stream>>>(
        value, WvT, nullptr, nullptr, vhT, nullptr);

    q2k2_kernel<<<2048, 256, 0, stream>>>(qh_hi, qh_lo, kh_hi, kh_lo, q2, k2);

    flash_rbf<<<1024, 256, 0, stream>>>(qh_hi, qh_lo, kh_hi, kh_lo,
                                        vhT, q2, k2, Sout, attn_bf);

    mfma_gemm512<ushort_t, 1, 0><<<1024, 256, 0, stream>>>(
        attn_bf, WoT, nullptr, out, nullptr, nullptr);
}

// Round 4
// 453.343 us; speedup vs baseline: 2.0009x; 1.5507x over previous
//
#include <hip/hip_runtime.h>

// (B,T,D,H,KD)=(8,1024,512,8,64), SIGMA=1.
// d_out: out [8*1024*512] f32, then attn_weights [64][1024][1024] f32.
// R4: canonical LDS staging (global_load_lds w=16, 2-barrier K-loop, XOR
// chunk swizzle) for all GEMMs and the fused flash kernel.  Split-bf16
// 3-pass MFMA on the q/k path, 1-pass bf16 elsewhere.

typedef float  floatx4 __attribute__((ext_vector_type(4)));
typedef short  short8  __attribute__((ext_vector_type(8)));
typedef unsigned short ushort_t;

#define MFMA16(a, b, c) __builtin_amdgcn_mfma_f32_16x16x32_bf16((a), (b), (c), 0, 0, 0)

__device__ inline ushort_t f2b(float f) {  // f32 -> bf16 bits, RNE
    unsigned u = __builtin_bit_cast(unsigned, f);
    unsigned r = u + 0x7fffu + ((u >> 16) & 1u);
    return (ushort_t)(r >> 16);
}
__device__ inline ushort_t f2b_trunc(float f) {
    return (ushort_t)(__builtin_bit_cast(unsigned, f) >> 16);
}
__device__ inline float b2f(ushort_t s) {
    return __builtin_bit_cast(float, (unsigned)s << 16);
}

// Async global->LDS, 16B per lane.  LDS dest = wave-uniform base + lane*16.
__device__ inline void gl_lds16(const void* g, void* l) {
    __builtin_amdgcn_global_load_lds(
        (const __attribute__((address_space(1))) unsigned int*)g,
        (__attribute__((address_space(3))) unsigned int*)l, 16, 0, 0);
}

// ---------------------------------------------------------------------------
// Weight transpose + split: WT[n][k] = W[k][n]; hi=bf16(w), lo=bf16(w-hi).
// ---------------------------------------------------------------------------
__global__ __launch_bounds__(256) void wt_cvt(
    const float* __restrict__ Wq, const float* __restrict__ Wk,
    const float* __restrict__ Wv, const float* __restrict__ Wo,
    ushort_t* __restrict__ qTh, ushort_t* __restrict__ qTl,
    ushort_t* __restrict__ kTh, ushort_t* __restrict__ kTl,
    ushort_t* __restrict__ vT,  ushort_t* __restrict__ oT)
{
    const int idx = blockIdx.x * 256 + threadIdx.x;  // n*512+k
    const int n = idx >> 9, k = idx & 511;
    const float* W; ushort_t* H; ushort_t* L; bool wl;
    switch (blockIdx.y) {
        case 0:  W = Wq; H = qTh; L = qTl; wl = true;  break;
        case 1:  W = Wk; H = kTh; L = kTl; wl = true;  break;
        case 2:  W = Wv; H = vT;  L = vT;  wl = false; break;
        default: W = Wo; H = oT;  L = oT;  wl = false; break;
    }
    float f = W[(size_t)k * 512 + n];
    ushort_t h = f2b(f);
    H[idx] = h;
    if (wl) L[idx] = f2b(f - b2f(h));
}

// ---------------------------------------------------------------------------
// LDS-staged MFMA GEMM, K=512, tile 64x64, BK=32, 256 threads (4 waves,
// wave w owns rows 16w..16w+15 x all 64 cols).  grid = 1024: mt=gid>>3,
// nt=gid&7 (gid%8 = n-panel -> per-XCD B locality).
// AT=float: A fp32 staged raw, hi/lo split after LDS read (NPASS=3 uses lo).
// AT=ushort_t: A bf16.  OUTMODE 0: f32.  1: bf16 hi+lo.  2: vhT[z][d][T].
// Chunk swizzle: LDS slot = (chunk + row) % nchunks -> conflict-free reads.
// ---------------------------------------------------------------------------
template <typename AT, int NPASS, int OUTMODE>
__global__ __launch_bounds__(256) void gemm_lds(
    const AT* __restrict__ A, const ushort_t* __restrict__ BTh,
    const ushort_t* __restrict__ BTl, float* __restrict__ outF,
    ushort_t* __restrict__ outH, ushort_t* __restrict__ outL)
{
    constexpr bool AF = (sizeof(AT) == 4);
    __shared__ __align__(16) float    sAf[AF ? 64 * 32 : 4];   // fp32 A tile
    __shared__ __align__(16) ushort_t sAb[AF ? 8 : 64 * 32];   // bf16 A tile
    __shared__ __align__(16) ushort_t sBh[64 * 32];
    __shared__ __align__(16) ushort_t sBl[NPASS == 3 ? 64 * 32 : 8];

    const int tid = threadIdx.x;
    const int w = tid >> 6, lane = tid & 63;
    const int l15 = lane & 15, quad = lane >> 4;
    const int gid = blockIdx.x;
    const int m0 = (gid >> 3) * 64, n0 = (gid & 7) * 64;

    floatx4 acc[4];
#pragma unroll
    for (int i = 0; i < 4; ++i) acc[i] = (floatx4){0.f, 0.f, 0.f, 0.f};

    for (int it = 0; it < 16; ++it) {
        const int k0 = it * 32;
        // ---- stage tiles (async, 16B/lane) ----
        if constexpr (AF) {
            // A tile 64x32 f32 = 8KB: rows of 8 chunks, swizzled.
#pragma unroll
            for (int t = 0; t < 2; ++t) {
                const int c = (w * 2 + t) * 64 + lane;
                const int row = c >> 3, slot = c & 7, kch = (slot - row) & 7;
                gl_lds16((const float*)A + (size_t)(m0 + row) * 512 + k0 + kch * 4,
                         (char*)sAf + (size_t)(w * 2 + t) * 1024);
            }
        } else {
            // A tile 64x32 bf16 = 4KB: rows of 4 chunks.
            const int c = w * 64 + lane;
            const int row = c >> 2, slot = c & 3, kch = (slot - row) & 3;
            gl_lds16((const ushort_t*)A + (size_t)(m0 + row) * 512 + k0 + kch * 8,
                     (char*)sAb + (size_t)w * 1024);
        }
        {
            const int c = w * 64 + lane;
            const int row = c >> 2, slot = c & 3, kch = (slot - row) & 3;
            const size_t ge = (size_t)(n0 + row) * 512 + k0 + kch * 8;
            gl_lds16(BTh + ge, (char*)sBh + (size_t)w * 1024);
            if (NPASS == 3)
                gl_lds16(BTl + ge, (char*)sBl + (size_t)w * 1024);
        }
        __syncthreads();

        // ---- fragments ----
        short8 ah, al;
        {
            const int row = 16 * w + l15;
            if constexpr (AF) {
                float4 f0 = *(const float4*)&sAf[row * 32 + ((quad * 2 + row) & 7) * 4];
                float4 f1 = *(const float4*)&sAf[row * 32 + ((quad * 2 + 1 + row) & 7) * 4];
                float fv[8] = {f0.x, f0.y, f0.z, f0.w, f1.x, f1.y, f1.z, f1.w};
#pragma unroll
                for (int j = 0; j < 8; ++j) {
                    ushort_t h = f2b(fv[j]);
                    ah[j] = (short)h;
                    if (NPASS == 3) al[j] = (short)f2b(fv[j] - b2f(h));
                }
            } else {
                ah = *(const short8*)&sAb[row * 32 + ((quad + row) & 3) * 8];
            }
        }
        short8 bh[4], bl[4];
#pragma unroll
        for (int ni = 0; ni < 4; ++ni) {
            const int row = ni * 16 + l15;
            const int off = row * 32 + ((quad + row) & 3) * 8;
            bh[ni] = *(const short8*)&sBh[off];
            if (NPASS == 3) bl[ni] = *(const short8*)&sBl[off];
        }
        // ---- MFMAs ----
#pragma unroll
        for (int ni = 0; ni < 4; ++ni) {
            acc[ni] = MFMA16(ah, bh[ni], acc[ni]);
            if (NPASS == 3) {
                acc[ni] = MFMA16(al, bh[ni], acc[ni]);
                acc[ni] = MFMA16(ah, bl[ni], acc[ni]);
            }
        }
        __syncthreads();
    }

    // ---- epilogue ----
#pragma unroll
    for (int ni = 0; ni < 4; ++ni) {
        const int n = n0 + ni * 16 + l15;
#pragma unroll
        for (int r = 0; r < 4; ++r) {
            const int m = m0 + 16 * w + quad * 4 + r;
            const float v = acc[ni][r];
            if (OUTMODE == 0) {
                outF[(size_t)m * 512 + n] = v;
            } else if (OUTMODE == 1) {
                ushort_t h = f2b(v);
                outH[(size_t)m * 512 + n] = h;
                outL[(size_t)m * 512 + n] = f2b(v - b2f(h));
            } else {
                const int b = m >> 10, t = m & 1023, hh = n >> 6, d = n & 63;
                outH[((size_t)(b * 8 + hh) * 64 + d) * 1024 + t] = f2b(v);
            }
        }
    }
}

// ---------------------------------------------------------------------------
// Per-head squared norms: q2[z][t] = sum_d (hi+lo)^2.
// ---------------------------------------------------------------------------
__global__ __launch_bounds__(256) void q2k2_kernel(
    const ushort_t* __restrict__ qh_hi, const ushort_t* __restrict__ qh_lo,
    const ushort_t* __restrict__ kh_hi, const ushort_t* __restrict__ kh_lo,
    float* __restrict__ q2, float* __restrict__ k2)
{
    const int wave = threadIdx.x >> 6, lane = threadIdx.x & 63;
    const int m = blockIdx.x * 4 + wave;
    const int b = m >> 10, t = m & 1023;
    const size_t base = (size_t)m * 512 + lane * 8;

    float sq = 0.f, sk = 0.f;
    short8 qh = *(const short8*)(qh_hi + base);
    short8 ql = *(const short8*)(qh_lo + base);
    short8 kh = *(const short8*)(kh_hi + base);
    short8 kl = *(const short8*)(kh_lo + base);
#pragma unroll
    for (int j = 0; j < 8; ++j) {
        float qv = b2f((ushort_t)qh[j]) + b2f((ushort_t)ql[j]);
        float kv = b2f((ushort_t)kh[j]) + b2f((ushort_t)kl[j]);
        sq = fmaf(qv, qv, sq);
        sk = fmaf(kv, kv, sk);
    }
#pragma unroll
    for (int off = 1; off < 8; off <<= 1) {
        sq += __shfl_xor(sq, off);
        sk += __shfl_xor(sk, off);
    }
    if ((lane & 7) == 0) {
        const int h = lane >> 3;
        q2[(size_t)(b * 8 + h) * 1024 + t] = sq;
        k2[(size_t)(b * 8 + h) * 1024 + t] = sk;
    }
}

// ---------------------------------------------------------------------------
// Fused flash: block = (z, 64 q-rows); gid = qt*64+z so gid%8==z%8 (XCD L2
// locality for K/V).  Per 64-col tile: stage Khi/Klo/V^T (3x8KB, swizzled)
// -> barrier -> QK 3-pass MFMA -> exp -> S store + P LDS strip -> SV MFMA
// -> barrier.  K/V loaded once per block instead of once per wave.
// ---------------------------------------------------------------------------
__global__ __launch_bounds__(256) void flash_rbf(
    const ushort_t* __restrict__ qh_hi, const ushort_t* __restrict__ qh_lo,
    const ushort_t* __restrict__ kh_hi, const ushort_t* __restrict__ kh_lo,
    const ushort_t* __restrict__ vhT, const float* __restrict__ q2,
    const float* __restrict__ k2, float* __restrict__ S,
    ushort_t* __restrict__ attn)
{
    __shared__ __align__(16) ushort_t sKh[64 * 64];
    __shared__ __align__(16) ushort_t sKl[64 * 64];
    __shared__ __align__(16) ushort_t sV [64 * 64];
    __shared__ __align__(16) ushort_t P  [64 * 72];

    const int tid = threadIdx.x;
    const int w = tid >> 6, lane = tid & 63;
    const int l15 = lane & 15, quad = lane >> 4;
    const int gid = blockIdx.x;
    const int z = gid & 63, qt = gid >> 6;
    const int b = z >> 3, h = z & 7;
    const int q0 = qt * 64;

    // Q fragments (registers, whole block).
    const size_t qrow = (size_t)(b * 1024 + q0 + 16 * w + l15) * 512 + h * 64 + quad * 8;
    short8 aqh[2], aql[2];
    aqh[0] = *(const short8*)(qh_hi + qrow);
    aqh[1] = *(const short8*)(qh_hi + qrow + 32);
    aql[0] = *(const short8*)(qh_lo + qrow);
    aql[1] = *(const short8*)(qh_lo + qrow + 32);

    float q2v[4];
#pragma unroll
    for (int r = 0; r < 4; ++r)
        q2v[r] = q2[(size_t)z * 1024 + q0 + 16 * w + quad * 4 + r];

    floatx4 oacc[4];
#pragma unroll
    for (int i = 0; i < 4; ++i) oacc[i] = (floatx4){0.f, 0.f, 0.f, 0.f};

    const size_t Sz = (size_t)z << 20;

    for (int ct = 0; ct < 16; ++ct) {
        const int col0 = ct * 64;

        // ---- stage K hi/lo + V^T tiles (rows of 8 chunks, swizzled) ----
#pragma unroll
        for (int t = 0; t < 2; ++t) {
            const int c = (w * 2 + t) * 64 + lane;
            const int row = c >> 3, slot = c & 7, dch = (slot - row) & 7;
            const size_t ke = (size_t)(b * 1024 + col0 + row) * 512 + h * 64 + dch * 8;
            const size_t ve = ((size_t)z * 64 + row) * 1024 + col0 + dch * 8;
            char* dst = (char*)0;
            gl_lds16(kh_hi + ke, (char*)sKh + (size_t)(w * 2 + t) * 1024);
            gl_lds16(kh_lo + ke, (char*)sKl + (size_t)(w * 2 + t) * 1024);
            gl_lds16(vhT + ve,  (char*)sV  + (size_t)(w * 2 + t) * 1024);
            (void)dst;
        }
        float k2v[4];
#pragma unroll
        for (int j = 0; j < 4; ++j)
            k2v[j] = k2[(size_t)z * 1024 + col0 + j * 16 + l15];
        __syncthreads();

        // ---- QK^T, 3-pass split ----
        floatx4 s[4];
#pragma unroll
        for (int j = 0; j < 4; ++j) {
            const int row = j * 16 + l15;
            const int base = row * 64;
            short8 kh0 = *(const short8*)&sKh[base + ((quad + row) & 7) * 8];
            short8 kh1 = *(const short8*)&sKh[base + ((quad + 4 + row) & 7) * 8];
            short8 kl0 = *(const short8*)&sKl[base + ((quad + row) & 7) * 8];
            short8 kl1 = *(const short8*)&sKl[base + ((quad + 4 + row) & 7) * 8];
            s[j] = (floatx4){0.f, 0.f, 0.f, 0.f};
            s[j] = MFMA16(aqh[0], kh0, s[j]);
            s[j] = MFMA16(aqh[1], kh1, s[j]);
            s[j] = MFMA16(aql[0], kh0, s[j]);
            s[j] = MFMA16(aql[1], kh1, s[j]);
            s[j] = MFMA16(aqh[0], kl0, s[j]);
            s[j] = MFMA16(aqh[1], kl1, s[j]);
        }

        // ---- V fragments ----
        short8 gv0[4], gv1[4];
#pragma unroll
        for (int j2 = 0; j2 < 4; ++j2) {
            const int row = j2 * 16 + l15;
            const int base = row * 64;
            gv0[j2] = *(const short8*)&sV[base + ((quad + row) & 7) * 8];
            gv1[j2] = *(const short8*)&sV[base + ((quad + 4 + row) & 7) * 8];
        }

        // ---- exp, S store, P pack ----
#pragma unroll
        for (int j = 0; j < 4; ++j) {
#pragma unroll
            for (int r = 0; r < 4; ++r) {
                const float val = __expf(2.f * s[j][r] - q2v[r] - k2v[j]);
                const int row = q0 + 16 * w + quad * 4 + r;
                S[Sz + (size_t)row * 1024 + col0 + j * 16 + l15] = val;
                P[(16 * w + quad * 4 + r) * 72 + j * 16 + l15] = f2b_trunc(val);
            }
        }

        // ---- P readback (A-layout, wave-local) + S@V ----
        short8 pf0 = *(const short8*)&P[(16 * w + l15) * 72 + quad * 8];
        short8 pf1 = *(const short8*)&P[(16 * w + l15) * 72 + 32 + quad * 8];
#pragma unroll
        for (int j2 = 0; j2 < 4; ++j2) {
            oacc[j2] = MFMA16(pf0, gv0[j2], oacc[j2]);
            oacc[j2] = MFMA16(pf1, gv1[j2], oacc[j2]);
        }
        __syncthreads();
    }

#pragma unroll
    for (int j2 = 0; j2 < 4; ++j2)
#pragma unroll
        for (int r = 0; r < 4; ++r) {
            const int row = q0 + 16 * w + quad * 4 + r;
            attn[(size_t)(b * 1024 + row) * 512 + h * 64 + j2 * 16 + l15] =
                f2b(oacc[j2][r]);
        }
}

extern "C" void kernel_launch(void* const* d_in, const int* in_sizes, int n_in,
                              void* d_out, int out_size, void* d_ws, size_t ws_size,
                              hipStream_t stream)
{
    const float* query = (const float*)d_in[0];
    const float* key   = (const float*)d_in[1];
    const float* value = (const float*)d_in[2];
    const float* Wq    = (const float*)d_in[3];
    const float* Wk    = (const float*)d_in[4];
    const float* Wv    = (const float*)d_in[5];
    const float* Wo    = (const float*)d_in[6];

    float* out  = (float*)d_out;
    float* Sout = out + (size_t)8192 * 512;

    const size_t NE = (size_t)8192 * 512;
    ushort_t* qh_hi   = (ushort_t*)d_ws;
    ushort_t* qh_lo   = qh_hi + NE;
    ushort_t* kh_hi   = qh_lo + NE;
    ushort_t* kh_lo   = kh_hi + NE;
    ushort_t* vhT     = kh_lo + NE;
    ushort_t* attn_bf = vhT + NE;
    ushort_t* WqT_hi  = attn_bf + NE;
    ushort_t* WqT_lo  = WqT_hi + 262144;
    ushort_t* WkT_hi  = WqT_lo + 262144;
    ushort_t* WkT_lo  = WkT_hi + 262144;
    ushort_t* WvT     = WkT_lo + 262144;
    ushort_t* WoT     = WvT + 262144;
    float*    q2      = (float*)(WoT + 262144);
    float*    k2      = q2 + 65536;

    wt_cvt<<<dim3(1024, 4), 256, 0, stream>>>(Wq, Wk, Wv, Wo, WqT_hi, WqT_lo,
                                              WkT_hi, WkT_lo, WvT, WoT);

    gemm_lds<float, 3, 1><<<1024, 256, 0, stream>>>(
        query, WqT_hi, WqT_lo, nullptr, qh_hi, qh_lo);
    gemm_lds<float, 3, 1><<<1024, 256, 0, stream>>>(
        key, WkT_hi, WkT_lo, nullptr, kh_hi, kh_lo);
    gemm_lds<float, 1, 2><<<1024, 256, 0, stream>>>(
        value, WvT, nullptr, nullptr, vhT, nullptr);

    q2k2_kernel<<<2048, 256, 0, stream>>>(qh_hi, qh_lo, kh_hi, kh_lo, q2, k2);

    flash_rbf<<<1024, 256, 0, stream>>>(qh_hi, qh_lo, kh_hi, kh_lo,
                                        vhT, q2, k2, Sout, attn_bf);

    gemm_lds<ushort_t, 1, 0><<<1024, 256, 0, stream>>>(
        attn_bf, WoT, nullptr, out, nullptr, nullptr);
}